// Round 4
// baseline (733.337 us; speedup 1.0000x reference)
//
#include <hip/hip_runtime.h>
#include <math.h>

#define NN   100000
#define E1N  3200000
#define C1N  25000
#define E2N  800000
#define C2N  6250
#define BN   64

#define NB    196     // dst buckets (both levels): 196*512 >= 100000, 196*128 >= 25000
#define EPB4  2048    // int4 units per count/scatter block (8192 edges)

// ---------------- node feature transforms ----------------

__global__ void node1_k(const float* __restrict__ x, const float* __restrict__ W1,
                        const float* __restrict__ att1,
                        float* __restrict__ h, float* __restrict__ ad, float* __restrict__ as_){
  int n = blockIdx.x * blockDim.x + threadIdx.x;
  if (n >= NN) return;
  float x0 = x[n*3+0], x1 = x[n*3+1], x2 = x[n*3+2];
  float a = 0.f, b = 0.f;
  #pragma unroll
  for (int j = 0; j < 16; ++j){
    float v = x0*W1[j] + x1*W1[16+j] + x2*W1[32+j];
    h[(size_t)n*16 + j] = v;
    a += v * att1[j];
    b += v * att1[16+j];
  }
  ad[n] = a; as_[n] = b;
}

__global__ void node2_k(const float* __restrict__ hp, const float* __restrict__ W2,
                        const float* __restrict__ att2,
                        float* __restrict__ h2, float* __restrict__ ad2, float* __restrict__ as2){
  int n = blockIdx.x * blockDim.x + threadIdx.x;
  if (n >= C1N) return;
  float hin[16];
  #pragma unroll
  for (int f = 0; f < 16; ++f) hin[f] = hp[(size_t)n*16 + f];
  float a = 0.f, b = 0.f;
  #pragma unroll
  for (int j = 0; j < 32; ++j){
    float v = 0.f;
    #pragma unroll
    for (int f = 0; f < 16; ++f) v += hin[f] * W2[f*32 + j];
    h2[(size_t)n*32 + j] = v;
    a += v * att2[j];
    b += v * att2[32 + j];
  }
  ad2[n] = a; as2[n] = b;
}

// ---------------- bucket sort (LDS histograms, no device atomics) ----------------

// per-block LDS histogram of dst>>SHIFT; counts to cnt[bucket*B + block]
template<int SHIFT>
__global__ void bucket_count_k(const int* __restrict__ dst, int* __restrict__ cnt,
                               int B, int E4){
  __shared__ int hist[NB];
  int t = threadIdx.x;
  if (t < NB) hist[t] = 0;
  __syncthreads();
  int q0 = blockIdx.x * EPB4;
  int qe = min(q0 + EPB4, E4);
  for (int q = q0 + t; q < qe; q += 256){
    int4 d4 = ((const int4*)dst)[q];
    atomicAdd(&hist[d4.x >> SHIFT], 1);
    atomicAdd(&hist[d4.y >> SHIFT], 1);
    atomicAdd(&hist[d4.z >> SHIFT], 1);
    atomicAdd(&hist[d4.w >> SHIFT], 1);
  }
  __syncthreads();
  if (t < NB) cnt[t * B + blockIdx.x] = hist[t];
}

#define SCAN_T 256
#define SCAN_E 4

__global__ void scan_block_k(const int* __restrict__ in, int* __restrict__ out,
                             int* __restrict__ bsum, int n){
  __shared__ int lds[SCAN_T];
  int t = threadIdx.x;
  int base = blockIdx.x * (SCAN_T*SCAN_E);
  int vals[SCAN_E];
  int acc = 0;
  #pragma unroll
  for (int k = 0; k < SCAN_E; ++k){
    int i = base + t*SCAN_E + k;
    vals[k] = (i < n) ? in[i] : 0;
    acc += vals[k];
  }
  lds[t] = acc;
  __syncthreads();
  #pragma unroll
  for (int off = 1; off < SCAN_T; off <<= 1){
    int v = (t >= off) ? lds[t-off] : 0;
    __syncthreads();
    lds[t] += v;
    __syncthreads();
  }
  int run = (t > 0) ? lds[t-1] : 0;
  #pragma unroll
  for (int k = 0; k < SCAN_E; ++k){
    int i = base + t*SCAN_E + k;
    run += vals[k];
    if (i < n) out[i] = run;
  }
  if (t == SCAN_T-1) bsum[blockIdx.x] = lds[SCAN_T-1];
}

__global__ void scan_top_k(int* __restrict__ bsum, int nb){
  if (threadIdx.x == 0){
    int run = 0;
    for (int b = 0; b < nb; ++b){ run += bsum[b]; bsum[b] = run; }
  }
}

__global__ void scan_add_k(int* __restrict__ out, const int* __restrict__ bsum, int n){
  int b = blockIdx.x;
  if (b == 0) return;
  int add = bsum[b-1];
  int i0 = b*(SCAN_T*SCAN_E) + threadIdx.x;
  #pragma unroll
  for (int k = 0; k < SCAN_E; ++k){
    int i = i0 + k*SCAN_T;
    if (i < n) out[i] += add;
  }
}

// scatter edges into bucket-grouped order. pay.x = src | dstLocal<<20, pay.y = w bits.
// cursors live in LDS; device-atomic-free.
template<int SHIFT>
__global__ void bucket_scatter_k(const int* __restrict__ src, const int* __restrict__ dst,
                                 const float* __restrict__ w, const int* __restrict__ S,
                                 int B, int E4, int2* __restrict__ pay){
  __shared__ int cur[NB];
  int t = threadIdx.x;
  if (t < NB){
    int i = t * B + blockIdx.x;
    cur[t] = (i == 0) ? 0 : S[i-1];   // exclusive prefix from inclusive scan
  }
  __syncthreads();
  int q0 = blockIdx.x * EPB4;
  int qe = min(q0 + EPB4, E4);
  const int MASK = (1 << SHIFT) - 1;
  for (int q = q0 + t; q < qe; q += 256){
    int4 s4 = ((const int4*)src)[q];
    int4 d4 = ((const int4*)dst)[q];
    float4 w4 = ((const float4*)w)[q];
    int p;
    p = atomicAdd(&cur[d4.x >> SHIFT], 1);
    pay[p] = make_int2(s4.x | ((d4.x & MASK) << 20), __float_as_int(w4.x));
    p = atomicAdd(&cur[d4.y >> SHIFT], 1);
    pay[p] = make_int2(s4.y | ((d4.y & MASK) << 20), __float_as_int(w4.y));
    p = atomicAdd(&cur[d4.z >> SHIFT], 1);
    pay[p] = make_int2(s4.z | ((d4.z & MASK) << 20), __float_as_int(w4.z));
    p = atomicAdd(&cur[d4.w >> SHIFT], 1);
    pay[p] = make_int2(s4.w | ((d4.w & MASK) << 20), __float_as_int(w4.w));
  }
}

// ---------------- per-bucket LDS aggregation + relu + cluster max-pool ----------------
// One block per bucket. Softmax denom + D feature sums in LDS (stride D+1 to
// spread banks). Epilogue: out = relu(acc/s + bias), guarded atomicMax pool.
template<int D, int DPB>
__global__ void bucket_agg_k(const int* __restrict__ S, int B,
                             const int2* __restrict__ pay,
                             const float* __restrict__ ad, const float* __restrict__ as_,
                             const float* __restrict__ h, const float* __restrict__ bias,
                             const int* __restrict__ cl, unsigned* __restrict__ pooled,
                             int nDst){
  const int STR = D + 1;
  __shared__ float accS[DPB];
  __shared__ float accF[DPB * STR];
  __shared__ float adL[DPB];
  int t = threadIdx.x, b = blockIdx.x;
  for (int i = t; i < DPB; i += 256) accS[i] = 0.f;
  for (int i = t; i < DPB*STR; i += 256) accF[i] = 0.f;
  for (int i = t; i < DPB; i += 256){
    int gd = b * DPB + i;
    adL[i] = (gd < nDst) ? ad[gd] : 0.f;
  }
  __syncthreads();
  int beg = (b == 0) ? 0 : S[b * B - 1];
  int end = S[(b + 1) * B - 1];
  for (int p = beg + t; p < end; p += 256){
    int2 pv = pay[p];
    int sv = pv.x & 0xFFFFF;
    int dl = pv.x >> 20;
    float l = adL[dl] + as_[sv];
    l = l > 0.f ? l : 0.2f * l;
    float ex = __expf(l);
    atomicAdd(&accS[dl], ex);
    float c = ex * __int_as_float(pv.y);
    const float4* hs = (const float4*)(h + (size_t)sv * D);
    float* af = accF + dl * STR;
    #pragma unroll
    for (int j = 0; j < D/4; ++j){
      float4 hv = hs[j];
      atomicAdd(&af[j*4+0], c*hv.x);
      atomicAdd(&af[j*4+1], c*hv.y);
      atomicAdd(&af[j*4+2], c*hv.z);
      atomicAdd(&af[j*4+3], c*hv.w);
    }
  }
  __syncthreads();
  for (int d = t; d < DPB; d += 256){
    int gd = b * DPB + d;
    if (gd >= nDst) break;          // gd monotone in d
    float s = accS[d];
    float inv = s > 0.f ? 1.f/s : 0.f;   // no-edge node: out = relu(bias)
    int c = cl[gd];
    #pragma unroll
    for (int j = 0; j < D; ++j){
      float v = accF[d*STR + j] * inv + bias[j];
      v = v > 0.f ? v : 0.f;
      unsigned nbits = __float_as_uint(v);
      unsigned* addr = &pooled[(size_t)c*D + j];
      if (nbits > *addr) atomicMax(addr, nbits);  // monotonic: stale read is safe
    }
  }
}

// ---------------- fused readout (scatter-mean) + MLP head ----------------
// one block per graph; scans batch array (L2-resident), shfl-reduces partials.
__global__ void readout_head_k(const float* __restrict__ hm, const int* __restrict__ batch,
                               const float* __restrict__ Wfc1, const float* __restrict__ bfc1,
                               const float* __restrict__ Wfc2, const float* __restrict__ bfc2,
                               float* __restrict__ out){
  __shared__ float gs[32];
  __shared__ int cntS;
  int t = threadIdx.x, b = blockIdx.x;
  if (t < 32) gs[t] = 0.f;
  if (t == 0) cntS = 0;
  __syncthreads();
  float g[32];
  #pragma unroll
  for (int j = 0; j < 32; ++j) g[j] = 0.f;
  int lc = 0;
  for (int c = t; c < C2N; c += 256){
    if (batch[c] == b){
      lc++;
      const float4* hv = (const float4*)(hm + (size_t)c*32);
      #pragma unroll
      for (int j = 0; j < 8; ++j){
        float4 v = hv[j];
        g[j*4+0] += v.x; g[j*4+1] += v.y; g[j*4+2] += v.z; g[j*4+3] += v.w;
      }
    }
  }
  #pragma unroll
  for (int j = 0; j < 32; ++j){
    float v = g[j];
    v += __shfl_xor(v, 1);  v += __shfl_xor(v, 2);  v += __shfl_xor(v, 4);
    v += __shfl_xor(v, 8);  v += __shfl_xor(v, 16); v += __shfl_xor(v, 32);
    if ((t & 63) == 0) atomicAdd(&gs[j], v);
  }
  {
    int v = lc;
    v += __shfl_xor(v, 1);  v += __shfl_xor(v, 2);  v += __shfl_xor(v, 4);
    v += __shfl_xor(v, 8);  v += __shfl_xor(v, 16); v += __shfl_xor(v, 32);
    if ((t & 63) == 0) atomicAdd(&cntS, v);
  }
  __syncthreads();
  if (t < 64){
    float cnt = (float)cntS; if (cnt < 1.f) cnt = 1.f;
    float inv = 1.f / cnt;
    float acc = bfc1[t];
    #pragma unroll
    for (int j = 0; j < 32; ++j) acc += gs[j] * inv * Wfc1[j*64 + t];
    acc = acc > 0.f ? acc : 0.f;
    acc *= Wfc2[t];
    acc += __shfl_xor(acc, 1);  acc += __shfl_xor(acc, 2);  acc += __shfl_xor(acc, 4);
    acc += __shfl_xor(acc, 8);  acc += __shfl_xor(acc, 16); acc += __shfl_xor(acc, 32);
    if (t == 0) out[b] = acc + bfc2[0];
  }
}

// ---------------- launch ----------------

extern "C" void kernel_launch(void* const* d_in, const int* in_sizes, int n_in,
                              void* d_out, int out_size, void* d_ws, size_t ws_size,
                              hipStream_t stream) {
  const float* x        = (const float*)d_in[0];
  const int*   ei       = (const int*)  d_in[1];   // [2, E1]: src = ei, dst = ei+E1
  const float* ea       = (const float*)d_in[2];
  const int*   cluster1 = (const int*)  d_in[3];
  const int*   ei2      = (const int*)  d_in[4];   // [2, E2]
  const float* ea2      = (const float*)d_in[5];
  const int*   cluster2 = (const int*)  d_in[6];
  const int*   batch    = (const int*)  d_in[7];
  const float* W1   = (const float*)d_in[8];
  const float* att1 = (const float*)d_in[9];
  const float* b1   = (const float*)d_in[10];
  const float* W2   = (const float*)d_in[11];
  const float* att2 = (const float*)d_in[12];
  const float* b2   = (const float*)d_in[13];
  const float* Wfc1 = (const float*)d_in[14];
  const float* bfc1 = (const float*)d_in[15];
  const float* Wfc2 = (const float*)d_in[16];
  const float* bfc2 = (const float*)d_in[17];

  const int B1 = (E1N/4 + EPB4 - 1) / EPB4;    // 391
  const int B2 = (E2N/4 + EPB4 - 1) / EPB4;    // 98
  const int n1 = NB * B1;                      // 76636
  const int n2 = NB * B2;                      // 19208
  const int nb1 = (n1 + SCAN_T*SCAN_E - 1) / (SCAN_T*SCAN_E);  // 75
  const int nb2 = (n2 + SCAN_T*SCAN_E - 1) / (SCAN_T*SCAN_E);  // 19

  float* ws = (float*)d_ws;
  // ---- zero-initialized block (pool buffers only) ----
  float* hp   = ws;                          // C1N*16 (float bits via atomicMax)
  float* hm   = hp + (size_t)C1N*16;         // C2N*32
  char*  zend = (char*)(hm + (size_t)C2N*32);
  size_t zbytes = (size_t)(zend - (char*)ws);
  // ---- write-before-read block (16B aligned) ----
  size_t off16 = (zbytes + 15) & ~(size_t)15;
  int2*  pay1 = (int2*)((char*)ws + off16);  // E1N int2
  int2*  pay2 = pay1 + E1N;                  // E2N int2
  float* h1   = (float*)(pay2 + E2N);        // NN*16
  float* ad1  = h1  + (size_t)NN*16;         // NN
  float* as1  = ad1 + NN;                    // NN
  float* h2   = as1 + NN;                    // C1N*32
  float* ad2  = h2  + (size_t)C1N*32;        // C1N
  float* as2  = ad2 + C1N;                   // C1N
  int*   cnt1 = (int*)(as2 + C1N);           // n1
  int*   S1   = cnt1 + n1;                   // n1
  int*   cnt2 = S1   + n1;                   // n2
  int*   S2   = cnt2 + n2;                   // n2
  int*   bsum = S2   + n2;                   // 256

  hipMemsetAsync(ws, 0, zbytes, stream);

  // conv1
  node1_k<<<(NN + 255)/256, 256, 0, stream>>>(x, W1, att1, h1, ad1, as1);
  bucket_count_k<9><<<B1, 256, 0, stream>>>(ei + E1N, cnt1, B1, E1N/4);
  scan_block_k<<<nb1, SCAN_T, 0, stream>>>(cnt1, S1, bsum, n1);
  scan_top_k<<<1, 64, 0, stream>>>(bsum, nb1);
  scan_add_k<<<nb1, SCAN_T, 0, stream>>>(S1, bsum, n1);
  bucket_scatter_k<9><<<B1, 256, 0, stream>>>(ei, ei + E1N, ea, S1, B1, E1N/4, pay1);
  bucket_agg_k<16,512><<<NB, 256, 0, stream>>>(S1, B1, pay1, ad1, as1, h1, b1,
                                               cluster1, (unsigned*)hp, NN);
  // conv2
  node2_k<<<(C1N + 255)/256, 256, 0, stream>>>(hp, W2, att2, h2, ad2, as2);
  bucket_count_k<7><<<B2, 256, 0, stream>>>(ei2 + E2N, cnt2, B2, E2N/4);
  scan_block_k<<<nb2, SCAN_T, 0, stream>>>(cnt2, S2, bsum, n2);
  scan_top_k<<<1, 64, 0, stream>>>(bsum, nb2);
  scan_add_k<<<nb2, SCAN_T, 0, stream>>>(S2, bsum, n2);
  bucket_scatter_k<7><<<B2, 256, 0, stream>>>(ei2, ei2 + E2N, ea2, S2, B2, E2N/4, pay2);
  bucket_agg_k<32,128><<<NB, 256, 0, stream>>>(S2, B2, pay2, ad2, as2, h2, b2,
                                               cluster2, (unsigned*)hm, C1N);
  // readout + head
  readout_head_k<<<BN, 256, 0, stream>>>(hm, batch, Wfc1, bfc1, Wfc2, bfc2, (float*)d_out);
}

// Round 5
// 630.094 us; speedup vs baseline: 1.1639x; 1.1639x over previous
//
#include <hip/hip_runtime.h>
#include <math.h>

#define NN   100000
#define E1N  3200000
#define C1N  25000
#define E2N  800000
#define C2N  6250
#define BN   64

#define NB    1563    // buckets both levels: 1563*64 >= 100000, 1563*16 >= 25000
#define EPB4  2048    // int4 units per count/scatter block (8192 edges)

// ---------------- node feature transforms ----------------

__global__ void node1_k(const float* __restrict__ x, const float* __restrict__ W1,
                        const float* __restrict__ att1,
                        float* __restrict__ h, float* __restrict__ ad, float* __restrict__ as_){
  int n = blockIdx.x * blockDim.x + threadIdx.x;
  if (n >= NN) return;
  float x0 = x[n*3+0], x1 = x[n*3+1], x2 = x[n*3+2];
  float a = 0.f, b = 0.f;
  #pragma unroll
  for (int j = 0; j < 16; ++j){
    float v = x0*W1[j] + x1*W1[16+j] + x2*W1[32+j];
    h[(size_t)n*16 + j] = v;
    a += v * att1[j];
    b += v * att1[16+j];
  }
  ad[n] = a; as_[n] = b;
}

__global__ void node2_k(const float* __restrict__ hp, const float* __restrict__ W2,
                        const float* __restrict__ att2,
                        float* __restrict__ h2, float* __restrict__ ad2, float* __restrict__ as2){
  int n = blockIdx.x * blockDim.x + threadIdx.x;
  if (n >= C1N) return;
  float hin[16];
  #pragma unroll
  for (int f = 0; f < 16; ++f) hin[f] = hp[(size_t)n*16 + f];
  float a = 0.f, b = 0.f;
  #pragma unroll
  for (int j = 0; j < 32; ++j){
    float v = 0.f;
    #pragma unroll
    for (int f = 0; f < 16; ++f) v += hin[f] * W2[f*32 + j];
    h2[(size_t)n*32 + j] = v;
    a += v * att2[j];
    b += v * att2[32 + j];
  }
  ad2[n] = a; as2[n] = b;
}

// ---------------- bucket sort (LDS histograms/cursors, zero device atomics) ----------------

template<int SHIFT>
__global__ void bucket_count_k(const int* __restrict__ dst, int* __restrict__ cnt,
                               int B, int E4){
  __shared__ int hist[NB];
  int t = threadIdx.x;
  for (int i = t; i < NB; i += 256) hist[i] = 0;
  __syncthreads();
  int q0 = blockIdx.x * EPB4;
  int qe = min(q0 + EPB4, E4);
  for (int q = q0 + t; q < qe; q += 256){
    int4 d4 = ((const int4*)dst)[q];
    atomicAdd(&hist[d4.x >> SHIFT], 1);
    atomicAdd(&hist[d4.y >> SHIFT], 1);
    atomicAdd(&hist[d4.z >> SHIFT], 1);
    atomicAdd(&hist[d4.w >> SHIFT], 1);
  }
  __syncthreads();
  for (int i = t; i < NB; i += 256) cnt[i * B + blockIdx.x] = hist[i];
}

#define SCAN_T 256
#define SCAN_E 4

__global__ void scan_block_k(const int* __restrict__ in, int* __restrict__ out,
                             int* __restrict__ bsum, int n){
  __shared__ int lds[SCAN_T];
  int t = threadIdx.x;
  int base = blockIdx.x * (SCAN_T*SCAN_E);
  int vals[SCAN_E];
  int acc = 0;
  #pragma unroll
  for (int k = 0; k < SCAN_E; ++k){
    int i = base + t*SCAN_E + k;
    vals[k] = (i < n) ? in[i] : 0;
    acc += vals[k];
  }
  lds[t] = acc;
  __syncthreads();
  #pragma unroll
  for (int off = 1; off < SCAN_T; off <<= 1){
    int v = (t >= off) ? lds[t-off] : 0;
    __syncthreads();
    lds[t] += v;
    __syncthreads();
  }
  int run = (t > 0) ? lds[t-1] : 0;
  #pragma unroll
  for (int k = 0; k < SCAN_E; ++k){
    int i = base + t*SCAN_E + k;
    run += vals[k];
    if (i < n) out[i] = run;
  }
  if (t == SCAN_T-1) bsum[blockIdx.x] = lds[SCAN_T-1];
}

__global__ void scan_add_k(int* __restrict__ out, const int* __restrict__ bsum, int n){
  int b = blockIdx.x;
  if (b == 0) return;
  int add = bsum[b-1];
  int i0 = b*(SCAN_T*SCAN_E) + threadIdx.x;
  #pragma unroll
  for (int k = 0; k < SCAN_E; ++k){
    int i = i0 + k*SCAN_T;
    if (i < n) out[i] += add;
  }
}

// scatter into bucket-grouped order: pay.x = src | dstLocal<<20, pay.y = w bits
template<int SHIFT>
__global__ void bucket_scatter_k(const int* __restrict__ src, const int* __restrict__ dst,
                                 const float* __restrict__ w, const int* __restrict__ S,
                                 int B, int E4, int2* __restrict__ pay){
  __shared__ int cur[NB];
  int t = threadIdx.x;
  for (int i = t; i < NB; i += 256){
    int g = i * B + blockIdx.x;
    cur[i] = (g == 0) ? 0 : S[g-1];   // exclusive prefix from inclusive scan
  }
  __syncthreads();
  int q0 = blockIdx.x * EPB4;
  int qe = min(q0 + EPB4, E4);
  const int MASK = (1 << SHIFT) - 1;
  for (int q = q0 + t; q < qe; q += 256){
    int4 s4 = ((const int4*)src)[q];
    int4 d4 = ((const int4*)dst)[q];
    float4 w4 = ((const float4*)w)[q];
    int p;
    p = atomicAdd(&cur[d4.x >> SHIFT], 1);
    pay[p] = make_int2(s4.x | ((d4.x & MASK) << 20), __float_as_int(w4.x));
    p = atomicAdd(&cur[d4.y >> SHIFT], 1);
    pay[p] = make_int2(s4.y | ((d4.y & MASK) << 20), __float_as_int(w4.y));
    p = atomicAdd(&cur[d4.z >> SHIFT], 1);
    pay[p] = make_int2(s4.z | ((d4.z & MASK) << 20), __float_as_int(w4.z));
    p = atomicAdd(&cur[d4.w >> SHIFT], 1);
    pay[p] = make_int2(s4.w | ((d4.w & MASK) << 20), __float_as_int(w4.w));
  }
}

// ---------------- per-bucket LDS aggregation + relu + cluster max-pool ----------------
// One block per bucket (DPB dsts). LDS accumulators stride D+1 (odd -> spread banks).
template<int D, int DPB>
__global__ void bucket_agg_k(const int* __restrict__ S, int B,
                             const int2* __restrict__ pay,
                             const float* __restrict__ ad, const float* __restrict__ as_,
                             const float* __restrict__ h, const float* __restrict__ bias,
                             const int* __restrict__ cl, unsigned* __restrict__ pooled,
                             int nDst){
  const int STR = D + 1;
  __shared__ float accS[DPB];
  __shared__ float accF[DPB * STR];
  __shared__ float adL[DPB];
  int t = threadIdx.x, b = blockIdx.x;
  for (int i = t; i < DPB; i += 256){
    accS[i] = 0.f;
    int gd = b * DPB + i;
    adL[i] = (gd < nDst) ? ad[gd] : 0.f;
  }
  for (int i = t; i < DPB*STR; i += 256) accF[i] = 0.f;
  __syncthreads();
  int beg = (b == 0) ? 0 : S[b * B - 1];
  int end = S[(b + 1) * B - 1];
  for (int p = beg + t; p < end; p += 256){
    int2 pv = pay[p];
    int sv = pv.x & 0xFFFFF;
    int dl = pv.x >> 20;
    float l = adL[dl] + as_[sv];
    l = l > 0.f ? l : 0.2f * l;
    float ex = __expf(l);
    atomicAdd(&accS[dl], ex);
    float c = ex * __int_as_float(pv.y);
    const float4* hs = (const float4*)(h + (size_t)sv * D);
    float* af = accF + dl * STR;
    #pragma unroll
    for (int j = 0; j < D/4; ++j){
      float4 hv = hs[j];
      atomicAdd(&af[j*4+0], c*hv.x);
      atomicAdd(&af[j*4+1], c*hv.y);
      atomicAdd(&af[j*4+2], c*hv.z);
      atomicAdd(&af[j*4+3], c*hv.w);
    }
  }
  __syncthreads();
  for (int d = t; d < DPB; d += 256){
    int gd = b * DPB + d;
    if (gd >= nDst) break;          // gd monotone in d
    float s = accS[d];
    float inv = s > 0.f ? 1.f/s : 0.f;   // no-edge node: out = relu(bias)
    int c = cl[gd];
    #pragma unroll
    for (int j = 0; j < D; ++j){
      float v = accF[d*STR + j] * inv + bias[j];
      v = v > 0.f ? v : 0.f;
      unsigned nbits = __float_as_uint(v);
      unsigned* addr = &pooled[(size_t)c*D + j];
      if (nbits > *addr) atomicMax(addr, nbits);  // monotonic: stale read is safe
    }
  }
}

// ---------------- fused readout (scatter-mean) + MLP head ----------------

__global__ void readout_head_k(const float* __restrict__ hm, const int* __restrict__ batch,
                               const float* __restrict__ Wfc1, const float* __restrict__ bfc1,
                               const float* __restrict__ Wfc2, const float* __restrict__ bfc2,
                               float* __restrict__ out){
  __shared__ float gs[32];
  __shared__ int cntS;
  int t = threadIdx.x, b = blockIdx.x;
  if (t < 32) gs[t] = 0.f;
  if (t == 0) cntS = 0;
  __syncthreads();
  float g[32];
  #pragma unroll
  for (int j = 0; j < 32; ++j) g[j] = 0.f;
  int lc = 0;
  for (int c = t; c < C2N; c += 256){
    if (batch[c] == b){
      lc++;
      const float4* hv = (const float4*)(hm + (size_t)c*32);
      #pragma unroll
      for (int j = 0; j < 8; ++j){
        float4 v = hv[j];
        g[j*4+0] += v.x; g[j*4+1] += v.y; g[j*4+2] += v.z; g[j*4+3] += v.w;
      }
    }
  }
  #pragma unroll
  for (int j = 0; j < 32; ++j){
    float v = g[j];
    v += __shfl_xor(v, 1);  v += __shfl_xor(v, 2);  v += __shfl_xor(v, 4);
    v += __shfl_xor(v, 8);  v += __shfl_xor(v, 16); v += __shfl_xor(v, 32);
    if ((t & 63) == 0) atomicAdd(&gs[j], v);
  }
  {
    int v = lc;
    v += __shfl_xor(v, 1);  v += __shfl_xor(v, 2);  v += __shfl_xor(v, 4);
    v += __shfl_xor(v, 8);  v += __shfl_xor(v, 16); v += __shfl_xor(v, 32);
    if ((t & 63) == 0) atomicAdd(&cntS, v);
  }
  __syncthreads();
  if (t < 64){
    float cnt = (float)cntS; if (cnt < 1.f) cnt = 1.f;
    float inv = 1.f / cnt;
    float acc = bfc1[t];
    #pragma unroll
    for (int j = 0; j < 32; ++j) acc += gs[j] * inv * Wfc1[j*64 + t];
    acc = acc > 0.f ? acc : 0.f;
    acc *= Wfc2[t];
    acc += __shfl_xor(acc, 1);  acc += __shfl_xor(acc, 2);  acc += __shfl_xor(acc, 4);
    acc += __shfl_xor(acc, 8);  acc += __shfl_xor(acc, 16); acc += __shfl_xor(acc, 32);
    if (t == 0) out[b] = acc + bfc2[0];
  }
}

// ---------------- launch ----------------

extern "C" void kernel_launch(void* const* d_in, const int* in_sizes, int n_in,
                              void* d_out, int out_size, void* d_ws, size_t ws_size,
                              hipStream_t stream) {
  const float* x        = (const float*)d_in[0];
  const int*   ei       = (const int*)  d_in[1];   // [2, E1]: src = ei, dst = ei+E1
  const float* ea       = (const float*)d_in[2];
  const int*   cluster1 = (const int*)  d_in[3];
  const int*   ei2      = (const int*)  d_in[4];   // [2, E2]
  const float* ea2      = (const float*)d_in[5];
  const int*   cluster2 = (const int*)  d_in[6];
  const int*   batch    = (const int*)  d_in[7];
  const float* W1   = (const float*)d_in[8];
  const float* att1 = (const float*)d_in[9];
  const float* b1   = (const float*)d_in[10];
  const float* W2   = (const float*)d_in[11];
  const float* att2 = (const float*)d_in[12];
  const float* b2   = (const float*)d_in[13];
  const float* Wfc1 = (const float*)d_in[14];
  const float* bfc1 = (const float*)d_in[15];
  const float* Wfc2 = (const float*)d_in[16];
  const float* bfc2 = (const float*)d_in[17];

  const int B1 = (E1N/4 + EPB4 - 1) / EPB4;    // 391
  const int B2 = (E2N/4 + EPB4 - 1) / EPB4;    // 98
  const int n1 = NB * B1;                      // 611133
  const int n2 = NB * B2;                      // 153174
  const int nb1 = (n1 + SCAN_T*SCAN_E - 1) / (SCAN_T*SCAN_E);  // 597 (<=1024)
  const int nb2 = (n2 + SCAN_T*SCAN_E - 1) / (SCAN_T*SCAN_E);  // 150

  float* ws = (float*)d_ws;
  // ---- zero-initialized block (pool buffers only) ----
  float* hp   = ws;                          // C1N*16 (float bits via atomicMax)
  float* hm   = hp + (size_t)C1N*16;         // C2N*32
  char*  zend = (char*)(hm + (size_t)C2N*32);
  size_t zbytes = (size_t)(zend - (char*)ws);
  // ---- write-before-read block (16B aligned) ----
  size_t off16 = (zbytes + 15) & ~(size_t)15;
  int2*  pay1 = (int2*)((char*)ws + off16);  // E1N int2
  int2*  pay2 = pay1 + E1N;                  // E2N int2
  float* h1   = (float*)(pay2 + E2N);        // NN*16
  float* ad1  = h1  + (size_t)NN*16;         // NN
  float* as1  = ad1 + NN;                    // NN
  float* h2   = as1 + NN;                    // C1N*32
  float* ad2  = h2  + (size_t)C1N*32;        // C1N
  float* as2  = ad2 + C1N;                   // C1N
  int*   cnt1 = (int*)(as2 + C1N);           // n1
  int*   S1   = cnt1 + n1;                   // n1
  int*   cnt2 = S1   + n1;                   // n2
  int*   S2   = cnt2 + n2;                   // n2
  int*   bsum = S2   + n2;                   // 1024
  int*   bsumT= bsum + 1024;                 // 4 (dummy)

  hipMemsetAsync(ws, 0, zbytes, stream);

  // conv1 (DPB=64, SHIFT=6)
  node1_k<<<(NN + 255)/256, 256, 0, stream>>>(x, W1, att1, h1, ad1, as1);
  bucket_count_k<6><<<B1, 256, 0, stream>>>(ei + E1N, cnt1, B1, E1N/4);
  scan_block_k<<<nb1, SCAN_T, 0, stream>>>(cnt1, S1, bsum, n1);
  scan_block_k<<<1, SCAN_T, 0, stream>>>(bsum, bsum, bsumT, nb1);  // in-place top scan
  scan_add_k<<<nb1, SCAN_T, 0, stream>>>(S1, bsum, n1);
  bucket_scatter_k<6><<<B1, 256, 0, stream>>>(ei, ei + E1N, ea, S1, B1, E1N/4, pay1);
  bucket_agg_k<16,64><<<NB, 256, 0, stream>>>(S1, B1, pay1, ad1, as1, h1, b1,
                                              cluster1, (unsigned*)hp, NN);
  // conv2 (DPB=16, SHIFT=4)
  node2_k<<<(C1N + 255)/256, 256, 0, stream>>>(hp, W2, att2, h2, ad2, as2);
  bucket_count_k<4><<<B2, 256, 0, stream>>>(ei2 + E2N, cnt2, B2, E2N/4);
  scan_block_k<<<nb2, SCAN_T, 0, stream>>>(cnt2, S2, bsum, n2);
  scan_block_k<<<1, SCAN_T, 0, stream>>>(bsum, bsum, bsumT, nb2);
  scan_add_k<<<nb2, SCAN_T, 0, stream>>>(S2, bsum, n2);
  bucket_scatter_k<4><<<B2, 256, 0, stream>>>(ei2, ei2 + E2N, ea2, S2, B2, E2N/4, pay2);
  bucket_agg_k<32,16><<<NB, 256, 0, stream>>>(S2, B2, pay2, ad2, as2, h2, b2,
                                              cluster2, (unsigned*)hm, C1N);
  // readout + head
  readout_head_k<<<BN, 256, 0, stream>>>(hm, batch, Wfc1, bfc1, Wfc2, bfc2, (float*)d_out);
}

// Round 6
// 293.962 us; speedup vs baseline: 2.4947x; 2.1435x over previous
//
#include <hip/hip_runtime.h>
#include <math.h>

#define NN   100000
#define E1N  3200000
#define C1N  25000
#define E2N  800000
#define C2N  6250
#define BN   64

#define NB1   3125    // conv1 buckets: 3125*32 = 100000 exactly (DPB=32, SHIFT=5)
#define NB2   1563    // conv2 buckets: 1563*16 >= 25000     (DPB=16, SHIFT=4)
#define EPB4  2048    // int4 units per count/scatter block (8192 edges)

// ---------------- tiny precompute: factor attention through W ----------------
// u[0:3]=W1@att1[:16], u[3:6]=W1@att1[16:]; v[0:16]=W2@att2[:32], v[16:32]=W2@att2[32:]
__global__ void prep_k(const float* __restrict__ W1, const float* __restrict__ att1,
                       const float* __restrict__ W2, const float* __restrict__ att2,
                       float* __restrict__ u, float* __restrict__ v){
  int t = threadIdx.x;
  if (t < 3){
    float a = 0.f, b = 0.f;
    for (int j = 0; j < 16; ++j){ a += W1[t*16+j]*att1[j]; b += W1[t*16+j]*att1[16+j]; }
    u[t] = a; u[3+t] = b;
  }
  if (t >= 8 && t < 24){
    int f = t - 8;
    float a = 0.f, b = 0.f;
    for (int j = 0; j < 32; ++j){ a += W2[f*32+j]*att2[j]; b += W2[f*32+j]*att2[32+j]; }
    v[f] = a; v[16+f] = b;
  }
}

// ---------------- node passes (no h materialization) ----------------

// ad1 = x . u_d ; xp = (x0,x1,x2, x . u_s)
__global__ void node1_k(const float* __restrict__ x, const float* __restrict__ u,
                        float* __restrict__ ad, float4* __restrict__ xp){
  int n = blockIdx.x * blockDim.x + threadIdx.x;
  if (n >= NN) return;
  float x0 = x[n*3+0], x1 = x[n*3+1], x2 = x[n*3+2];
  ad[n] = x0*u[0] + x1*u[1] + x2*u[2];
  xp[n] = make_float4(x0, x1, x2, x0*u[3] + x1*u[4] + x2*u[5]);
}

// ad2 = hp . v_d ; as2 = hp . v_s
__global__ void node2_k(const float* __restrict__ hp, const float* __restrict__ v,
                        float* __restrict__ ad2, float* __restrict__ as2){
  int n = blockIdx.x * blockDim.x + threadIdx.x;
  if (n >= C1N) return;
  const float4* hr = (const float4*)(hp + (size_t)n*16);
  float a = 0.f, b = 0.f;
  #pragma unroll
  for (int j = 0; j < 4; ++j){
    float4 hv = hr[j];
    a += hv.x*v[j*4+0] + hv.y*v[j*4+1] + hv.z*v[j*4+2] + hv.w*v[j*4+3];
    b += hv.x*v[16+j*4+0] + hv.y*v[16+j*4+1] + hv.z*v[16+j*4+2] + hv.w*v[16+j*4+3];
  }
  ad2[n] = a; as2[n] = b;
}

// ---------------- bucket sort (LDS histograms/cursors, zero device atomics) ----------------

template<int NBUK, int SHIFT>
__global__ void bucket_count_k(const int* __restrict__ dst, int* __restrict__ cnt,
                               int B, int E4){
  __shared__ int hist[NBUK];
  int t = threadIdx.x;
  for (int i = t; i < NBUK; i += 256) hist[i] = 0;
  __syncthreads();
  int q0 = blockIdx.x * EPB4;
  int qe = min(q0 + EPB4, E4);
  for (int q = q0 + t; q < qe; q += 256){
    int4 d4 = ((const int4*)dst)[q];
    atomicAdd(&hist[d4.x >> SHIFT], 1);
    atomicAdd(&hist[d4.y >> SHIFT], 1);
    atomicAdd(&hist[d4.z >> SHIFT], 1);
    atomicAdd(&hist[d4.w >> SHIFT], 1);
  }
  __syncthreads();
  for (int i = t; i < NBUK; i += 256) cnt[(size_t)i * B + blockIdx.x] = hist[i];
}

#define SCAN_T 256

template<int E>
__global__ void scan_block_k(const int* __restrict__ in, int* __restrict__ out,
                             int* __restrict__ bsum, int n){
  __shared__ int lds[SCAN_T];
  int t = threadIdx.x;
  int base = blockIdx.x * (SCAN_T*E);
  int vals[E];
  int acc = 0;
  #pragma unroll
  for (int k = 0; k < E; ++k){
    int i = base + t*E + k;
    vals[k] = (i < n) ? in[i] : 0;
    acc += vals[k];
  }
  lds[t] = acc;
  __syncthreads();
  #pragma unroll
  for (int off = 1; off < SCAN_T; off <<= 1){
    int v = (t >= off) ? lds[t-off] : 0;
    __syncthreads();
    lds[t] += v;
    __syncthreads();
  }
  int run = (t > 0) ? lds[t-1] : 0;
  #pragma unroll
  for (int k = 0; k < E; ++k){
    int i = base + t*E + k;
    run += vals[k];
    if (i < n) out[i] = run;
  }
  if (t == SCAN_T-1) bsum[blockIdx.x] = lds[SCAN_T-1];
}

__global__ void scan_add_k(int* __restrict__ out, const int* __restrict__ bsum, int n){
  int b = blockIdx.x;
  if (b == 0) return;
  int add = bsum[b-1];
  int i0 = b*(SCAN_T*4) + threadIdx.x;
  #pragma unroll
  for (int k = 0; k < 4; ++k){
    int i = i0 + k*SCAN_T;
    if (i < n) out[i] += add;
  }
}

// scatter into bucket-grouped order: pay.x = src | dstLocal<<20, pay.y = w bits
template<int NBUK, int SHIFT>
__global__ void bucket_scatter_k(const int* __restrict__ src, const int* __restrict__ dst,
                                 const float* __restrict__ w, const int* __restrict__ S,
                                 int B, int E4, int2* __restrict__ pay){
  __shared__ int cur[NBUK];
  int t = threadIdx.x;
  for (int i = t; i < NBUK; i += 256){
    size_t g = (size_t)i * B + blockIdx.x;
    cur[i] = (g == 0) ? 0 : S[g-1];   // exclusive prefix from inclusive scan
  }
  __syncthreads();
  int q0 = blockIdx.x * EPB4;
  int qe = min(q0 + EPB4, E4);
  const int MASK = (1 << SHIFT) - 1;
  for (int q = q0 + t; q < qe; q += 256){
    int4 s4 = ((const int4*)src)[q];
    int4 d4 = ((const int4*)dst)[q];
    float4 w4 = ((const float4*)w)[q];
    int p;
    p = atomicAdd(&cur[d4.x >> SHIFT], 1);
    pay[p] = make_int2(s4.x | ((d4.x & MASK) << 20), __float_as_int(w4.x));
    p = atomicAdd(&cur[d4.y >> SHIFT], 1);
    pay[p] = make_int2(s4.y | ((d4.y & MASK) << 20), __float_as_int(w4.y));
    p = atomicAdd(&cur[d4.z >> SHIFT], 1);
    pay[p] = make_int2(s4.z | ((d4.z & MASK) << 20), __float_as_int(w4.z));
    p = atomicAdd(&cur[d4.w >> SHIFT], 1);
    pay[p] = make_int2(s4.w | ((d4.w & MASK) << 20), __float_as_int(w4.w));
  }
}

// ---------------- conv1 aggregation: accumulate raw x (3-dim), W1 in epilogue ----------------
// acc per dst: [s, sum c*x0, sum c*x1, sum c*x2], stride 5 (odd -> banks spread).
__global__ void agg1_k(const int* __restrict__ S, int B, const int2* __restrict__ pay,
                       const float* __restrict__ ad, const float4* __restrict__ xp,
                       const float* __restrict__ W1, const float* __restrict__ b1,
                       const int* __restrict__ cl, unsigned* __restrict__ pooled){
  __shared__ float accX[32*5];
  __shared__ float adL[32];
  int t = threadIdx.x, b = blockIdx.x;
  if (t < 160) accX[t] = 0.f;
  if (t < 32) adL[t] = ad[b*32 + t];        // 3125*32 == 100000: no guard needed
  __syncthreads();
  int beg = b ? S[(size_t)b*B - 1] : 0;
  int end = S[(size_t)(b+1)*B - 1];
  int p = beg + t;
  for (; p + 256 < end; p += 512){           // 2-edge unroll for MLP
    int2 pv0 = pay[p], pv1 = pay[p+256];
    float4 xv0 = xp[pv0.x & 0xFFFFF];
    float4 xv1 = xp[pv1.x & 0xFFFFF];
    int dl0 = pv0.x >> 20, dl1 = pv1.x >> 20;
    float l0 = adL[dl0] + xv0.w; l0 = l0 > 0.f ? l0 : 0.2f*l0;
    float l1 = adL[dl1] + xv1.w; l1 = l1 > 0.f ? l1 : 0.2f*l1;
    float ex0 = __expf(l0), ex1 = __expf(l1);
    float c0 = ex0 * __int_as_float(pv0.y), c1 = ex1 * __int_as_float(pv1.y);
    float* a0 = accX + dl0*5;
    atomicAdd(a0+0, ex0); atomicAdd(a0+1, c0*xv0.x);
    atomicAdd(a0+2, c0*xv0.y); atomicAdd(a0+3, c0*xv0.z);
    float* a1 = accX + dl1*5;
    atomicAdd(a1+0, ex1); atomicAdd(a1+1, c1*xv1.x);
    atomicAdd(a1+2, c1*xv1.y); atomicAdd(a1+3, c1*xv1.z);
  }
  if (p < end){
    int2 pv = pay[p];
    float4 xv = xp[pv.x & 0xFFFFF];
    int dl = pv.x >> 20;
    float l = adL[dl] + xv.w; l = l > 0.f ? l : 0.2f*l;
    float ex = __expf(l);
    float c = ex * __int_as_float(pv.y);
    float* a = accX + dl*5;
    atomicAdd(a+0, ex); atomicAdd(a+1, c*xv.x);
    atomicAdd(a+2, c*xv.y); atomicAdd(a+3, c*xv.z);
  }
  __syncthreads();
  // epilogue: h_agg = accX @ W1; out = relu(h_agg/s + b1); pool max into hp
  for (int i = t; i < 512; i += 256){
    int d = i >> 4, j = i & 15;
    float s = accX[d*5];
    float inv = s > 0.f ? 1.f/s : 0.f;       // no-edge node: out = relu(b1)
    float vl = (accX[d*5+1]*W1[j] + accX[d*5+2]*W1[16+j] + accX[d*5+3]*W1[32+j])*inv + b1[j];
    vl = vl > 0.f ? vl : 0.f;
    int c = cl[b*32 + d];
    unsigned nb_ = __float_as_uint(vl);
    unsigned* addr = pooled + (size_t)c*16 + j;
    if (nb_ > *addr) atomicMax(addr, nb_);   // monotonic: stale read safe
  }
}

// ---------------- conv2 aggregation: accumulate pre-W2 hp (16-dim), W2 in epilogue ----------------
__global__ void agg2_k(const int* __restrict__ S, int B, const int2* __restrict__ pay,
                       const float* __restrict__ ad2, const float* __restrict__ as2,
                       const float* __restrict__ hp, const float* __restrict__ W2,
                       const float* __restrict__ b2, const int* __restrict__ cl2,
                       unsigned* __restrict__ pooledm){
  __shared__ float accH[16*17];   // per dst: 16 feature sums + s at [16]
  __shared__ float adL[16];
  int t = threadIdx.x, b = blockIdx.x;
  for (int i = t; i < 272; i += 256) accH[i] = 0.f;
  if (t < 16){ int gd = b*16 + t; adL[t] = (gd < C1N) ? ad2[gd] : 0.f; }
  __syncthreads();
  int beg = b ? S[(size_t)b*B - 1] : 0;
  int end = S[(size_t)(b+1)*B - 1];
  for (int p = beg + t; p < end; p += 256){
    int2 pv = pay[p];
    int sv = pv.x & 0xFFFFF, dl = pv.x >> 20;
    float l = adL[dl] + as2[sv];
    l = l > 0.f ? l : 0.2f*l;
    float ex = __expf(l);
    float c = ex * __int_as_float(pv.y);
    const float4* hs = (const float4*)(hp + (size_t)sv*16);
    float* a = accH + dl*17;
    atomicAdd(a+16, ex);
    #pragma unroll
    for (int j = 0; j < 4; ++j){
      float4 hv = hs[j];
      atomicAdd(a+j*4+0, c*hv.x);
      atomicAdd(a+j*4+1, c*hv.y);
      atomicAdd(a+j*4+2, c*hv.z);
      atomicAdd(a+j*4+3, c*hv.w);
    }
  }
  __syncthreads();
  for (int i = t; i < 512; i += 256){
    int d = i >> 5, j = i & 31;
    int gd = b*16 + d;
    if (gd < C1N){
      float s = accH[d*17+16];
      float inv = s > 0.f ? 1.f/s : 0.f;
      float vl = 0.f;
      #pragma unroll
      for (int f = 0; f < 16; ++f) vl += accH[d*17+f] * W2[f*32+j];
      vl = vl*inv + b2[j];
      vl = vl > 0.f ? vl : 0.f;
      int c = cl2[gd];
      unsigned nb_ = __float_as_uint(vl);
      unsigned* addr = pooledm + (size_t)c*32 + j;
      if (nb_ > *addr) atomicMax(addr, nb_);
    }
  }
}

// ---------------- fused readout (scatter-mean) + MLP head ----------------

__global__ void readout_head_k(const float* __restrict__ hm, const int* __restrict__ batch,
                               const float* __restrict__ Wfc1, const float* __restrict__ bfc1,
                               const float* __restrict__ Wfc2, const float* __restrict__ bfc2,
                               float* __restrict__ out){
  __shared__ float gs[32];
  __shared__ int cntS;
  int t = threadIdx.x, b = blockIdx.x;
  if (t < 32) gs[t] = 0.f;
  if (t == 0) cntS = 0;
  __syncthreads();
  float g[32];
  #pragma unroll
  for (int j = 0; j < 32; ++j) g[j] = 0.f;
  int lc = 0;
  for (int c = t; c < C2N; c += 256){
    if (batch[c] == b){
      lc++;
      const float4* hv = (const float4*)(hm + (size_t)c*32);
      #pragma unroll
      for (int j = 0; j < 8; ++j){
        float4 v = hv[j];
        g[j*4+0] += v.x; g[j*4+1] += v.y; g[j*4+2] += v.z; g[j*4+3] += v.w;
      }
    }
  }
  #pragma unroll
  for (int j = 0; j < 32; ++j){
    float v = g[j];
    v += __shfl_xor(v, 1);  v += __shfl_xor(v, 2);  v += __shfl_xor(v, 4);
    v += __shfl_xor(v, 8);  v += __shfl_xor(v, 16); v += __shfl_xor(v, 32);
    if ((t & 63) == 0) atomicAdd(&gs[j], v);
  }
  {
    int v = lc;
    v += __shfl_xor(v, 1);  v += __shfl_xor(v, 2);  v += __shfl_xor(v, 4);
    v += __shfl_xor(v, 8);  v += __shfl_xor(v, 16); v += __shfl_xor(v, 32);
    if ((t & 63) == 0) atomicAdd(&cntS, v);
  }
  __syncthreads();
  if (t < 64){
    float cnt = (float)cntS; if (cnt < 1.f) cnt = 1.f;
    float inv = 1.f / cnt;
    float acc = bfc1[t];
    #pragma unroll
    for (int j = 0; j < 32; ++j) acc += gs[j] * inv * Wfc1[j*64 + t];
    acc = acc > 0.f ? acc : 0.f;
    acc *= Wfc2[t];
    acc += __shfl_xor(acc, 1);  acc += __shfl_xor(acc, 2);  acc += __shfl_xor(acc, 4);
    acc += __shfl_xor(acc, 8);  acc += __shfl_xor(acc, 16); acc += __shfl_xor(acc, 32);
    if (t == 0) out[b] = acc + bfc2[0];
  }
}

// ---------------- launch ----------------

extern "C" void kernel_launch(void* const* d_in, const int* in_sizes, int n_in,
                              void* d_out, int out_size, void* d_ws, size_t ws_size,
                              hipStream_t stream) {
  const float* x        = (const float*)d_in[0];
  const int*   ei       = (const int*)  d_in[1];   // [2, E1]: src = ei, dst = ei+E1
  const float* ea       = (const float*)d_in[2];
  const int*   cluster1 = (const int*)  d_in[3];
  const int*   ei2      = (const int*)  d_in[4];   // [2, E2]
  const float* ea2      = (const float*)d_in[5];
  const int*   cluster2 = (const int*)  d_in[6];
  const int*   batch    = (const int*)  d_in[7];
  const float* W1   = (const float*)d_in[8];
  const float* att1 = (const float*)d_in[9];
  const float* b1   = (const float*)d_in[10];
  const float* W2   = (const float*)d_in[11];
  const float* att2 = (const float*)d_in[12];
  const float* b2   = (const float*)d_in[13];
  const float* Wfc1 = (const float*)d_in[14];
  const float* bfc1 = (const float*)d_in[15];
  const float* Wfc2 = (const float*)d_in[16];
  const float* bfc2 = (const float*)d_in[17];

  const int B1 = (E1N/4 + EPB4 - 1) / EPB4;    // 391
  const int B2 = (E2N/4 + EPB4 - 1) / EPB4;    // 98
  const int n1 = NB1 * B1;                     // 1,221,875
  const int n2 = NB2 * B2;                     // 153,174
  const int nb1 = (n1 + SCAN_T*4 - 1) / (SCAN_T*4);  // 1194 (<=2048 top capacity)
  const int nb2 = (n2 + SCAN_T*4 - 1) / (SCAN_T*4);  // 150

  float* ws = (float*)d_ws;
  // ---- zero-initialized block (pool buffers only) ----
  float* hp   = ws;                          // C1N*16 (float bits via atomicMax)
  float* hm   = hp + (size_t)C1N*16;         // C2N*32
  char*  zend = (char*)(hm + (size_t)C2N*32);
  size_t zbytes = (size_t)(zend - (char*)ws);
  // ---- write-before-read block (16B aligned) ----
  size_t off16 = (zbytes + 15) & ~(size_t)15;
  int2*   pay1 = (int2*)((char*)ws + off16); // E1N int2 (25.6MB, 16B-multiple)
  int2*   pay2 = pay1 + E1N;                 // E2N int2
  float4* xp   = (float4*)(pay2 + E2N);      // NN float4 (16B aligned)
  float*  ad1  = (float*)(xp + NN);          // NN
  float*  ad2  = ad1 + NN;                   // C1N
  float*  as2  = ad2 + C1N;                  // C1N
  float*  uv   = as2 + C1N;                  // 40 (u[6] at +0, v[32] at +8)
  int*    cnt1 = (int*)(uv + 40);            // n1
  int*    S1   = cnt1 + n1;                  // n1
  int*    cnt2 = S1   + n1;                  // n2
  int*    S2   = cnt2 + n2;                  // n2
  int*    bsum = S2   + n2;                  // 2048
  int*    bsumT= bsum + 2048;                // 8 (dummy)

  hipMemsetAsync(ws, 0, zbytes, stream);

  prep_k<<<1, 64, 0, stream>>>(W1, att1, W2, att2, uv, uv + 8);

  // conv1 (DPB=32, SHIFT=5)
  node1_k<<<(NN + 255)/256, 256, 0, stream>>>(x, uv, ad1, xp);
  bucket_count_k<NB1,5><<<B1, 256, 0, stream>>>(ei + E1N, cnt1, B1, E1N/4);
  scan_block_k<4><<<nb1, SCAN_T, 0, stream>>>(cnt1, S1, bsum, n1);
  scan_block_k<8><<<1, SCAN_T, 0, stream>>>(bsum, bsum, bsumT, nb1);  // in-place top scan
  scan_add_k<<<nb1, SCAN_T, 0, stream>>>(S1, bsum, n1);
  bucket_scatter_k<NB1,5><<<B1, 256, 0, stream>>>(ei, ei + E1N, ea, S1, B1, E1N/4, pay1);
  agg1_k<<<NB1, 256, 0, stream>>>(S1, B1, pay1, ad1, xp, W1, b1, cluster1, (unsigned*)hp);

  // conv2 (DPB=16, SHIFT=4)
  node2_k<<<(C1N + 255)/256, 256, 0, stream>>>(hp, uv + 8, ad2, as2);
  bucket_count_k<NB2,4><<<B2, 256, 0, stream>>>(ei2 + E2N, cnt2, B2, E2N/4);
  scan_block_k<4><<<nb2, SCAN_T, 0, stream>>>(cnt2, S2, bsum, n2);
  scan_block_k<8><<<1, SCAN_T, 0, stream>>>(bsum, bsum, bsumT, nb2);
  scan_add_k<<<nb2, SCAN_T, 0, stream>>>(S2, bsum, n2);
  bucket_scatter_k<NB2,4><<<B2, 256, 0, stream>>>(ei2, ei2 + E2N, ea2, S2, B2, E2N/4, pay2);
  agg2_k<<<NB2, 256, 0, stream>>>(S2, B2, pay2, ad2, as2, hp, W2, b2, cluster2, (unsigned*)hm);

  // readout + head
  readout_head_k<<<BN, 256, 0, stream>>>(hm, batch, Wfc1, bfc1, Wfc2, bfc2, (float*)d_out);
}

// Round 7
// 182.658 us; speedup vs baseline: 4.0148x; 1.6094x over previous
//
#include <hip/hip_runtime.h>
#include <math.h>

#define NN   100000
#define E1N  3200000
#define C1N  25000
#define E2N  800000
#define C2N  6250
#define BN   64

#define NB1   3125    // conv1 buckets: 3125*32 = 100000 exactly (DPB=32, SHIFT=5)
#define NB2   1563    // conv2 buckets: 1563*16 >= 25000     (DPB=16, SHIFT=4)
#define EPB4  2048    // int4 units per count/scatter block (8192 edges)

// ---------------- tiny precompute: factor attention through W ----------------
__global__ void prep_k(const float* __restrict__ W1, const float* __restrict__ att1,
                       const float* __restrict__ W2, const float* __restrict__ att2,
                       float* __restrict__ u, float* __restrict__ v){
  int t = threadIdx.x;
  if (t < 3){
    float a = 0.f, b = 0.f;
    for (int j = 0; j < 16; ++j){ a += W1[t*16+j]*att1[j]; b += W1[t*16+j]*att1[16+j]; }
    u[t] = a; u[3+t] = b;
  }
  if (t >= 8 && t < 24){
    int f = t - 8;
    float a = 0.f, b = 0.f;
    for (int j = 0; j < 32; ++j){ a += W2[f*32+j]*att2[j]; b += W2[f*32+j]*att2[32+j]; }
    v[f] = a; v[16+f] = b;
  }
}

// ---------------- node passes (no h materialization) ----------------

__global__ void node1_k(const float* __restrict__ x, const float* __restrict__ u,
                        float* __restrict__ ad, float4* __restrict__ xp){
  int n = blockIdx.x * blockDim.x + threadIdx.x;
  if (n >= NN) return;
  float x0 = x[n*3+0], x1 = x[n*3+1], x2 = x[n*3+2];
  ad[n] = x0*u[0] + x1*u[1] + x2*u[2];
  xp[n] = make_float4(x0, x1, x2, x0*u[3] + x1*u[4] + x2*u[5]);
}

__global__ void node2_k(const float* __restrict__ hp, const float* __restrict__ v,
                        float* __restrict__ ad2, float* __restrict__ as2){
  int n = blockIdx.x * blockDim.x + threadIdx.x;
  if (n >= C1N) return;
  const float4* hr = (const float4*)(hp + (size_t)n*16);
  float a = 0.f, b = 0.f;
  #pragma unroll
  for (int j = 0; j < 4; ++j){
    float4 hv = hr[j];
    a += hv.x*v[j*4+0] + hv.y*v[j*4+1] + hv.z*v[j*4+2] + hv.w*v[j*4+3];
    b += hv.x*v[16+j*4+0] + hv.y*v[16+j*4+1] + hv.z*v[16+j*4+2] + hv.w*v[16+j*4+3];
  }
  ad2[n] = a; as2[n] = b;
}

// ---------------- bucket sort (LDS histograms/cursors, zero device atomics) ----------------

template<int NBUK, int SHIFT>
__global__ void bucket_count_k(const int* __restrict__ dst, int* __restrict__ cnt,
                               int B, int E4){
  __shared__ int hist[NBUK];
  int t = threadIdx.x;
  for (int i = t; i < NBUK; i += 256) hist[i] = 0;
  __syncthreads();
  int q0 = blockIdx.x * EPB4;
  int qe = min(q0 + EPB4, E4);
  for (int q = q0 + t; q < qe; q += 256){
    int4 d4 = ((const int4*)dst)[q];
    atomicAdd(&hist[d4.x >> SHIFT], 1);
    atomicAdd(&hist[d4.y >> SHIFT], 1);
    atomicAdd(&hist[d4.z >> SHIFT], 1);
    atomicAdd(&hist[d4.w >> SHIFT], 1);
  }
  __syncthreads();
  for (int i = t; i < NBUK; i += 256) cnt[(size_t)i * B + blockIdx.x] = hist[i];
}

#define SCAN_T 256

template<int E>
__global__ void scan_block_k(const int* __restrict__ in, int* __restrict__ out,
                             int* __restrict__ bsum, int n){
  __shared__ int lds[SCAN_T];
  int t = threadIdx.x;
  int base = blockIdx.x * (SCAN_T*E);
  int vals[E];
  int acc = 0;
  #pragma unroll
  for (int k = 0; k < E; ++k){
    int i = base + t*E + k;
    vals[k] = (i < n) ? in[i] : 0;
    acc += vals[k];
  }
  lds[t] = acc;
  __syncthreads();
  #pragma unroll
  for (int off = 1; off < SCAN_T; off <<= 1){
    int v = (t >= off) ? lds[t-off] : 0;
    __syncthreads();
    lds[t] += v;
    __syncthreads();
  }
  int run = (t > 0) ? lds[t-1] : 0;
  #pragma unroll
  for (int k = 0; k < E; ++k){
    int i = base + t*E + k;
    run += vals[k];
    if (i < n) out[i] = run;
  }
  if (t == SCAN_T-1) bsum[blockIdx.x] = lds[SCAN_T-1];
}

__global__ void scan_add_k(int* __restrict__ out, const int* __restrict__ bsum, int n){
  int b = blockIdx.x;
  if (b == 0) return;
  int add = bsum[b-1];
  int i0 = b*(SCAN_T*4) + threadIdx.x;
  #pragma unroll
  for (int k = 0; k < 4; ++k){
    int i = i0 + k*SCAN_T;
    if (i < n) out[i] += add;
  }
}

// scatter into bucket-grouped order: pay.x = src | dstLocal<<20, pay.y = w bits
template<int NBUK, int SHIFT>
__global__ void bucket_scatter_k(const int* __restrict__ src, const int* __restrict__ dst,
                                 const float* __restrict__ w, const int* __restrict__ S,
                                 int B, int E4, int2* __restrict__ pay){
  __shared__ int cur[NBUK];
  int t = threadIdx.x;
  for (int i = t; i < NBUK; i += 256){
    size_t g = (size_t)i * B + blockIdx.x;
    cur[i] = (g == 0) ? 0 : S[g-1];   // exclusive prefix from inclusive scan
  }
  __syncthreads();
  int q0 = blockIdx.x * EPB4;
  int qe = min(q0 + EPB4, E4);
  const int MASK = (1 << SHIFT) - 1;
  for (int q = q0 + t; q < qe; q += 256){
    int4 s4 = ((const int4*)src)[q];
    int4 d4 = ((const int4*)dst)[q];
    float4 w4 = ((const float4*)w)[q];
    int p;
    p = atomicAdd(&cur[d4.x >> SHIFT], 1);
    pay[p] = make_int2(s4.x | ((d4.x & MASK) << 20), __float_as_int(w4.x));
    p = atomicAdd(&cur[d4.y >> SHIFT], 1);
    pay[p] = make_int2(s4.y | ((d4.y & MASK) << 20), __float_as_int(w4.y));
    p = atomicAdd(&cur[d4.z >> SHIFT], 1);
    pay[p] = make_int2(s4.z | ((d4.z & MASK) << 20), __float_as_int(w4.z));
    p = atomicAdd(&cur[d4.w >> SHIFT], 1);
    pay[p] = make_int2(s4.w | ((d4.w & MASK) << 20), __float_as_int(w4.w));
  }
}

// ---------------- conv1 agg: in-LDS counting sort by dl, register accumulation ----------------
// Per 1024-edge chunk: hist(1 atomic/edge) -> shfl-scan -> cursor place (1 atomic/edge)
// -> 8-lane group per dst accumulates run in registers, shfl-reduce, plain LDS add.
__global__ void agg1_k(const int* __restrict__ S, int B, const int2* __restrict__ pay,
                       const float* __restrict__ ad, const float4* __restrict__ xp,
                       const float* __restrict__ W1, const float* __restrict__ b1,
                       const int* __restrict__ cl, unsigned* __restrict__ pooled){
  __shared__ float accX[32*5];     // per dst: [s, sx0, sx1, sx2] stride 5
  __shared__ float adL[32];
  __shared__ int   hist[32], base_[32], cur[32];
  __shared__ int2  sorted[1024];
  int t = threadIdx.x, b = blockIdx.x;
  if (t < 160) accX[t] = 0.f;
  if (t < 32)  adL[t] = ad[b*32 + t];     // 3125*32 == 100000 exactly
  __syncthreads();
  int beg = b ? S[(size_t)b*B - 1] : 0;
  int end = S[(size_t)(b+1)*B - 1];

  for (int c0 = beg; c0 < end; c0 += 1024){
    if (t < 32){ hist[t] = 0; }
    __syncthreads();
    // phase A: stash + histogram
    int2 pv0, pv1, pv2, pv3; int d0=0,d1=0,d2=0,d3=0;
    bool v0 = c0 +          t < end;
    bool v1 = c0 + 256    + t < end;
    bool v2 = c0 + 512    + t < end;
    bool v3 = c0 + 768    + t < end;
    if (v0){ pv0 = pay[c0 +       t]; d0 = pv0.x >> 20; atomicAdd(&hist[d0], 1); }
    if (v1){ pv1 = pay[c0 + 256 + t]; d1 = pv1.x >> 20; atomicAdd(&hist[d1], 1); }
    if (v2){ pv2 = pay[c0 + 512 + t]; d2 = pv2.x >> 20; atomicAdd(&hist[d2], 1); }
    if (v3){ pv3 = pay[c0 + 768 + t]; d3 = pv3.x >> 20; atomicAdd(&hist[d3], 1); }
    __syncthreads();
    // phase B: 32-wide exclusive scan (wave 0)
    if (t < 32){
      int v = hist[t], inc = v;
      #pragma unroll
      for (int off = 1; off < 32; off <<= 1){
        int u_ = __shfl_up(inc, off);
        if (t >= off) inc += u_;
      }
      base_[t] = inc - v;
      cur[t]   = inc - v;
    }
    __syncthreads();
    // phase C: place into sorted runs
    if (v0){ sorted[atomicAdd(&cur[d0], 1)] = pv0; }
    if (v1){ sorted[atomicAdd(&cur[d1], 1)] = pv1; }
    if (v2){ sorted[atomicAdd(&cur[d2], 1)] = pv2; }
    if (v3){ sorted[atomicAdd(&cur[d3], 1)] = pv3; }
    __syncthreads();
    // phase D: 8-lane group g owns dst g
    {
      int g = t >> 3, lane = t & 7;
      int cnt = hist[g], bas = base_[g];
      float adg = adL[g];
      float aS = 0.f, a0 = 0.f, a1 = 0.f, a2 = 0.f;
      for (int k = lane; k < cnt; k += 8){
        int2 p = sorted[bas + k];
        float4 xv = xp[p.x & 0xFFFFF];
        float l = adg + xv.w; l = l > 0.f ? l : 0.2f*l;
        float ex = __expf(l);
        float c = ex * __int_as_float(p.y);
        aS += ex; a0 += c*xv.x; a1 += c*xv.y; a2 += c*xv.z;
      }
      #pragma unroll
      for (int off = 1; off < 8; off <<= 1){
        aS += __shfl_xor(aS, off); a0 += __shfl_xor(a0, off);
        a1 += __shfl_xor(a1, off); a2 += __shfl_xor(a2, off);
      }
      if (lane == 0){
        accX[g*5+0] += aS; accX[g*5+1] += a0;
        accX[g*5+2] += a1; accX[g*5+3] += a2;
      }
    }
    __syncthreads();
  }
  // epilogue: h_agg = accX @ W1; out = relu(h_agg/s + b1); guarded max-pool
  for (int i = t; i < 512; i += 256){
    int d = i >> 4, j = i & 15;
    float s = accX[d*5];
    float inv = s > 0.f ? 1.f/s : 0.f;       // no-edge node: out = relu(b1)
    float vl = (accX[d*5+1]*W1[j] + accX[d*5+2]*W1[16+j] + accX[d*5+3]*W1[32+j])*inv + b1[j];
    vl = vl > 0.f ? vl : 0.f;
    int c = cl[b*32 + d];
    unsigned nb_ = __float_as_uint(vl);
    unsigned* addr = pooled + (size_t)c*16 + j;
    if (nb_ > *addr) atomicMax(addr, nb_);   // monotonic: stale read safe
  }
}

// ---------------- conv2 agg: same counting-sort structure, 16-dim registers ----------------
__global__ void agg2_k(const int* __restrict__ S, int B, const int2* __restrict__ pay,
                       const float* __restrict__ ad2, const float* __restrict__ as2,
                       const float* __restrict__ hp, const float* __restrict__ W2,
                       const float* __restrict__ b2, const int* __restrict__ cl2,
                       unsigned* __restrict__ pooledm){
  __shared__ float accH[16*17];    // per dst: 16 feature sums + s at [16]
  __shared__ float adL[16];
  __shared__ int   hist[16], base_[16], cur[16];
  __shared__ int2  sorted[1024];
  int t = threadIdx.x, b = blockIdx.x;
  for (int i = t; i < 272; i += 256) accH[i] = 0.f;
  if (t < 16){ int gd = b*16 + t; adL[t] = (gd < C1N) ? ad2[gd] : 0.f; }
  __syncthreads();
  int beg = b ? S[(size_t)b*B - 1] : 0;
  int end = S[(size_t)(b+1)*B - 1];

  for (int c0 = beg; c0 < end; c0 += 1024){
    if (t < 16){ hist[t] = 0; }
    __syncthreads();
    int2 pv0, pv1, pv2, pv3; int d0=0,d1=0,d2=0,d3=0;
    bool v0 = c0 +          t < end;
    bool v1 = c0 + 256    + t < end;
    bool v2 = c0 + 512    + t < end;
    bool v3 = c0 + 768    + t < end;
    if (v0){ pv0 = pay[c0 +       t]; d0 = pv0.x >> 20; atomicAdd(&hist[d0], 1); }
    if (v1){ pv1 = pay[c0 + 256 + t]; d1 = pv1.x >> 20; atomicAdd(&hist[d1], 1); }
    if (v2){ pv2 = pay[c0 + 512 + t]; d2 = pv2.x >> 20; atomicAdd(&hist[d2], 1); }
    if (v3){ pv3 = pay[c0 + 768 + t]; d3 = pv3.x >> 20; atomicAdd(&hist[d3], 1); }
    __syncthreads();
    if (t < 16){
      int v = hist[t], inc = v;
      #pragma unroll
      for (int off = 1; off < 16; off <<= 1){
        int u_ = __shfl_up(inc, off);
        if (t >= off) inc += u_;
      }
      base_[t] = inc - v;
      cur[t]   = inc - v;
    }
    __syncthreads();
    if (v0){ sorted[atomicAdd(&cur[d0], 1)] = pv0; }
    if (v1){ sorted[atomicAdd(&cur[d1], 1)] = pv1; }
    if (v2){ sorted[atomicAdd(&cur[d2], 1)] = pv2; }
    if (v3){ sorted[atomicAdd(&cur[d3], 1)] = pv3; }
    __syncthreads();
    // phase D: 16-lane group g owns dst g
    {
      int g = t >> 4, lane = t & 15;
      int cnt = hist[g], bas = base_[g];
      float adg = adL[g];
      float aS = 0.f;
      float4 f0 = make_float4(0,0,0,0), f1 = make_float4(0,0,0,0);
      float4 f2 = make_float4(0,0,0,0), f3 = make_float4(0,0,0,0);
      for (int k = lane; k < cnt; k += 16){
        int2 p = sorted[bas + k];
        int sv = p.x & 0xFFFFF;
        float l = adg + as2[sv]; l = l > 0.f ? l : 0.2f*l;
        float ex = __expf(l);
        float c = ex * __int_as_float(p.y);
        const float4* hs = (const float4*)(hp + (size_t)sv*16);
        float4 h0 = hs[0], h1 = hs[1], h2 = hs[2], h3 = hs[3];
        aS += ex;
        f0.x += c*h0.x; f0.y += c*h0.y; f0.z += c*h0.z; f0.w += c*h0.w;
        f1.x += c*h1.x; f1.y += c*h1.y; f1.z += c*h1.z; f1.w += c*h1.w;
        f2.x += c*h2.x; f2.y += c*h2.y; f2.z += c*h2.z; f2.w += c*h2.w;
        f3.x += c*h3.x; f3.y += c*h3.y; f3.z += c*h3.z; f3.w += c*h3.w;
      }
      #pragma unroll
      for (int off = 1; off < 16; off <<= 1){
        aS += __shfl_xor(aS, off);
        f0.x += __shfl_xor(f0.x, off); f0.y += __shfl_xor(f0.y, off);
        f0.z += __shfl_xor(f0.z, off); f0.w += __shfl_xor(f0.w, off);
        f1.x += __shfl_xor(f1.x, off); f1.y += __shfl_xor(f1.y, off);
        f1.z += __shfl_xor(f1.z, off); f1.w += __shfl_xor(f1.w, off);
        f2.x += __shfl_xor(f2.x, off); f2.y += __shfl_xor(f2.y, off);
        f2.z += __shfl_xor(f2.z, off); f2.w += __shfl_xor(f2.w, off);
        f3.x += __shfl_xor(f3.x, off); f3.y += __shfl_xor(f3.y, off);
        f3.z += __shfl_xor(f3.z, off); f3.w += __shfl_xor(f3.w, off);
      }
      if (lane == 0){
        float* a = accH + g*17;
        a[0] += f0.x; a[1] += f0.y; a[2]  += f0.z; a[3]  += f0.w;
        a[4] += f1.x; a[5] += f1.y; a[6]  += f1.z; a[7]  += f1.w;
        a[8] += f2.x; a[9] += f2.y; a[10] += f2.z; a[11] += f2.w;
        a[12]+= f3.x; a[13]+= f3.y; a[14] += f3.z; a[15] += f3.w;
        a[16]+= aS;
      }
    }
    __syncthreads();
  }
  // epilogue: out = relu((accH @ W2)/s + b2); guarded max-pool into hm
  for (int i = t; i < 512; i += 256){
    int d = i >> 5, j = i & 31;
    int gd = b*16 + d;
    if (gd < C1N){
      float s = accH[d*17+16];
      float inv = s > 0.f ? 1.f/s : 0.f;
      float vl = 0.f;
      #pragma unroll
      for (int f = 0; f < 16; ++f) vl += accH[d*17+f] * W2[f*32+j];
      vl = vl*inv + b2[j];
      vl = vl > 0.f ? vl : 0.f;
      int c = cl2[gd];
      unsigned nb_ = __float_as_uint(vl);
      unsigned* addr = pooledm + (size_t)c*32 + j;
      if (nb_ > *addr) atomicMax(addr, nb_);
    }
  }
}

// ---------------- fused readout (scatter-mean) + MLP head ----------------

__global__ void readout_head_k(const float* __restrict__ hm, const int* __restrict__ batch,
                               const float* __restrict__ Wfc1, const float* __restrict__ bfc1,
                               const float* __restrict__ Wfc2, const float* __restrict__ bfc2,
                               float* __restrict__ out){
  __shared__ float gs[32];
  __shared__ int cntS;
  int t = threadIdx.x, b = blockIdx.x;
  if (t < 32) gs[t] = 0.f;
  if (t == 0) cntS = 0;
  __syncthreads();
  float g[32];
  #pragma unroll
  for (int j = 0; j < 32; ++j) g[j] = 0.f;
  int lc = 0;
  for (int c = t; c < C2N; c += 256){
    if (batch[c] == b){
      lc++;
      const float4* hv = (const float4*)(hm + (size_t)c*32);
      #pragma unroll
      for (int j = 0; j < 8; ++j){
        float4 v = hv[j];
        g[j*4+0] += v.x; g[j*4+1] += v.y; g[j*4+2] += v.z; g[j*4+3] += v.w;
      }
    }
  }
  #pragma unroll
  for (int j = 0; j < 32; ++j){
    float v = g[j];
    v += __shfl_xor(v, 1);  v += __shfl_xor(v, 2);  v += __shfl_xor(v, 4);
    v += __shfl_xor(v, 8);  v += __shfl_xor(v, 16); v += __shfl_xor(v, 32);
    if ((t & 63) == 0) atomicAdd(&gs[j], v);
  }
  {
    int v = lc;
    v += __shfl_xor(v, 1);  v += __shfl_xor(v, 2);  v += __shfl_xor(v, 4);
    v += __shfl_xor(v, 8);  v += __shfl_xor(v, 16); v += __shfl_xor(v, 32);
    if ((t & 63) == 0) atomicAdd(&cntS, v);
  }
  __syncthreads();
  if (t < 64){
    float cnt = (float)cntS; if (cnt < 1.f) cnt = 1.f;
    float inv = 1.f / cnt;
    float acc = bfc1[t];
    #pragma unroll
    for (int j = 0; j < 32; ++j) acc += gs[j] * inv * Wfc1[j*64 + t];
    acc = acc > 0.f ? acc : 0.f;
    acc *= Wfc2[t];
    acc += __shfl_xor(acc, 1);  acc += __shfl_xor(acc, 2);  acc += __shfl_xor(acc, 4);
    acc += __shfl_xor(acc, 8);  acc += __shfl_xor(acc, 16); acc += __shfl_xor(acc, 32);
    if (t == 0) out[b] = acc + bfc2[0];
  }
}

// ---------------- launch ----------------

extern "C" void kernel_launch(void* const* d_in, const int* in_sizes, int n_in,
                              void* d_out, int out_size, void* d_ws, size_t ws_size,
                              hipStream_t stream) {
  const float* x        = (const float*)d_in[0];
  const int*   ei       = (const int*)  d_in[1];   // [2, E1]: src = ei, dst = ei+E1
  const float* ea       = (const float*)d_in[2];
  const int*   cluster1 = (const int*)  d_in[3];
  const int*   ei2      = (const int*)  d_in[4];   // [2, E2]
  const float* ea2      = (const float*)d_in[5];
  const int*   cluster2 = (const int*)  d_in[6];
  const int*   batch    = (const int*)  d_in[7];
  const float* W1   = (const float*)d_in[8];
  const float* att1 = (const float*)d_in[9];
  const float* b1   = (const float*)d_in[10];
  const float* W2   = (const float*)d_in[11];
  const float* att2 = (const float*)d_in[12];
  const float* b2   = (const float*)d_in[13];
  const float* Wfc1 = (const float*)d_in[14];
  const float* bfc1 = (const float*)d_in[15];
  const float* Wfc2 = (const float*)d_in[16];
  const float* bfc2 = (const float*)d_in[17];

  const int B1 = (E1N/4 + EPB4 - 1) / EPB4;    // 391
  const int B2 = (E2N/4 + EPB4 - 1) / EPB4;    // 98
  const int n1 = NB1 * B1;                     // 1,221,875
  const int n2 = NB2 * B2;                     // 153,174
  const int nb1 = (n1 + SCAN_T*4 - 1) / (SCAN_T*4);  // 1194 (<=2048 top capacity)
  const int nb2 = (n2 + SCAN_T*4 - 1) / (SCAN_T*4);  // 150

  float* ws = (float*)d_ws;
  // ---- zero-initialized block (pool buffers only) ----
  float* hp   = ws;                          // C1N*16 (float bits via atomicMax)
  float* hm   = hp + (size_t)C1N*16;         // C2N*32
  char*  zend = (char*)(hm + (size_t)C2N*32);
  size_t zbytes = (size_t)(zend - (char*)ws);
  // ---- write-before-read block (16B aligned) ----
  size_t off16 = (zbytes + 15) & ~(size_t)15;
  int2*   pay1 = (int2*)((char*)ws + off16); // E1N int2
  int2*   pay2 = pay1 + E1N;                 // E2N int2
  float4* xp   = (float4*)(pay2 + E2N);      // NN float4
  float*  ad1  = (float*)(xp + NN);          // NN
  float*  ad2  = ad1 + NN;                   // C1N
  float*  as2  = ad2 + C1N;                  // C1N
  float*  uv   = as2 + C1N;                  // 40 (u[6] at +0, v[32] at +8)
  int*    cnt1 = (int*)(uv + 40);            // n1
  int*    S1   = cnt1 + n1;                  // n1
  int*    cnt2 = S1   + n1;                  // n2
  int*    S2   = cnt2 + n2;                  // n2
  int*    bsum = S2   + n2;                  // 2048
  int*    bsumT= bsum + 2048;                // 8 (dummy)

  hipMemsetAsync(ws, 0, zbytes, stream);

  prep_k<<<1, 64, 0, stream>>>(W1, att1, W2, att2, uv, uv + 8);

  // conv1 (DPB=32, SHIFT=5)
  node1_k<<<(NN + 255)/256, 256, 0, stream>>>(x, uv, ad1, xp);
  bucket_count_k<NB1,5><<<B1, 256, 0, stream>>>(ei + E1N, cnt1, B1, E1N/4);
  scan_block_k<4><<<nb1, SCAN_T, 0, stream>>>(cnt1, S1, bsum, n1);
  scan_block_k<8><<<1, SCAN_T, 0, stream>>>(bsum, bsum, bsumT, nb1);  // in-place top scan
  scan_add_k<<<nb1, SCAN_T, 0, stream>>>(S1, bsum, n1);
  bucket_scatter_k<NB1,5><<<B1, 256, 0, stream>>>(ei, ei + E1N, ea, S1, B1, E1N/4, pay1);
  agg1_k<<<NB1, 256, 0, stream>>>(S1, B1, pay1, ad1, xp, W1, b1, cluster1, (unsigned*)hp);

  // conv2 (DPB=16, SHIFT=4)
  node2_k<<<(C1N + 255)/256, 256, 0, stream>>>(hp, uv + 8, ad2, as2);
  bucket_count_k<NB2,4><<<B2, 256, 0, stream>>>(ei2 + E2N, cnt2, B2, E2N/4);
  scan_block_k<4><<<nb2, SCAN_T, 0, stream>>>(cnt2, S2, bsum, n2);
  scan_block_k<8><<<1, SCAN_T, 0, stream>>>(bsum, bsum, bsumT, nb2);
  scan_add_k<<<nb2, SCAN_T, 0, stream>>>(S2, bsum, n2);
  bucket_scatter_k<NB2,4><<<B2, 256, 0, stream>>>(ei2, ei2 + E2N, ea2, S2, B2, E2N/4, pay2);
  agg2_k<<<NB2, 256, 0, stream>>>(S2, B2, pay2, ad2, as2, hp, W2, b2, cluster2, (unsigned*)hm);

  // readout + head
  readout_head_k<<<BN, 256, 0, stream>>>(hm, batch, Wfc1, bfc1, Wfc2, bfc2, (float*)d_out);
}